// Round 2
// baseline (764.445 us; speedup 1.0000x reference)
//
#include <hip/hip_runtime.h>
#include <hip/hip_bf16.h>
#include <math.h>

typedef unsigned long long u64;
typedef unsigned int u32;

#define C_NUM 80
#define TOPK 1000
#define CAP 2048
#define HB 128
#define SCORE_THR 0.05f
#define IOU_THR 0.5f
#define GRID_SCAN 256

// correctly-rounded-ish f32 exp via double (matched reference bit-exact in round 1)
__device__ __forceinline__ float exp_cr(float x) {
    return (float)exp((double)x);
}

// Exact f32 replication of reference decode + clip (no FMA contraction).
__device__ __forceinline__ void decode_box(const float* __restrict__ anch,
                                           const float* __restrict__ reg,
                                           int a, float fw, float fh, float4* out) {
#pragma clang fp contract(off)
    float a0 = anch[(size_t)a * 4 + 0], a1 = anch[(size_t)a * 4 + 1];
    float a2 = anch[(size_t)a * 4 + 2], a3 = anch[(size_t)a * 4 + 3];
    float d0 = reg[(size_t)a * 4 + 0], d1 = reg[(size_t)a * 4 + 1];
    float d2 = reg[(size_t)a * 4 + 2], d3 = reg[(size_t)a * 4 + 3];
    float w = a2 - a0, h = a3 - a1;
    float cx = a0 + 0.5f * w, cy = a1 + 0.5f * h;
    float dx = d0 * 0.1f, dy = d1 * 0.1f, dw = d2 * 0.2f, dh = d3 * 0.2f;
    float t1 = dx * w; float pcx = cx + t1;
    float t2 = dy * h; float pcy = cy + t2;
    float pw = exp_cr(dw) * w;
    float ph = exp_cr(dh) * h;
    float x1 = pcx - 0.5f * pw, y1 = pcy - 0.5f * ph;
    float x2 = pcx + 0.5f * pw, y2 = pcy + 0.5f * ph;
    x1 = fminf(fmaxf(x1, 0.0f), fw);
    y1 = fminf(fmaxf(y1, 0.0f), fh);
    x2 = fminf(fmaxf(x2, 0.0f), fw);
    y2 = fminf(fmaxf(y2, 0.0f), fh);
    *out = make_float4(x1, y1, x2, y2);
}

__global__ void zero_kernel(u32* __restrict__ histG, u32* __restrict__ cntG) {
    int t = blockIdx.x * 256 + threadIdx.x;
    if (t < C_NUM * HB) histG[t] = 0u;
    if (t < C_NUM) cntG[t] = 0u;
}

// Coalesced float4 walk over [A][80]; per-class 128-bucket LDS histogram of the
// top score bits (buckets cover [0.5,1.0) in 1/256 steps; bucket 0 = "below",
// skipped entirely: its count is never needed and same-address atomics serialize).
__global__ __launch_bounds__(1024)
void hist_kernel(const float4* __restrict__ cls4, u32* __restrict__ histG, int nvec) {
    __shared__ u32 h[C_NUM * HB];
    int tid = threadIdx.x;
    for (int i = tid; i < C_NUM * HB; i += 1024) h[i] = 0u;
    __syncthreads();
    int gid = blockIdx.x * 1024 + tid;
    const int stride = GRID_SCAN * 1024;            // float4 units
    const int dC = (stride * 4) % C_NUM;            // class advance per grid step
    int c0 = (gid * 4) % C_NUM;
    for (int v = gid; v < nvec; v += stride) {
        float4 f = cls4[v];
        float e[4] = {f.x, f.y, f.z, f.w};
        int cc = c0;
#pragma unroll
        for (int k = 0; k < 4; ++k) {
            int t = (((int)__float_as_uint(e[k])) - 0x3F000000) >> 16;
            if (t > 0) {
                t = t > HB - 1 ? HB - 1 : t;
                atomicAdd(&h[cc * HB + t], 1u);
            }
            cc++; if (cc == C_NUM) cc = 0;
        }
        c0 += dC; if (c0 >= C_NUM) c0 -= C_NUM;
    }
    __syncthreads();
    for (int i = tid; i < C_NUM * HB; i += 1024) {
        u32 v = h[i];
        if (v) atomicAdd(&histG[i], v);
    }
}

// Per-class suffix-sum over 128 buckets; threshold = lower bit-edge of the
// largest bucket b with suffix count >= TOPK (0 if none -> take everything >=0).
__global__ __launch_bounds__(HB)
void thr_kernel(const u32* __restrict__ histG, u32* __restrict__ thrG) {
    __shared__ u32 s[HB];
    __shared__ int bsel;
    int c = blockIdx.x, tid = threadIdx.x;
    if (tid == 0) bsel = 0;
    s[tid] = histG[c * HB + tid];
    __syncthreads();
    for (int d = 1; d < HB; d <<= 1) {
        u32 v = s[tid] + ((tid + d < HB) ? s[tid + d] : 0u);
        __syncthreads();
        s[tid] = v;
        __syncthreads();
    }
    u32 me = s[tid];
    u32 nxt = (tid < HB - 1) ? s[tid + 1] : 0u;
    if (me >= (u32)TOPK && (tid == HB - 1 || nxt < (u32)TOPK)) bsel = tid;
    __syncthreads();
    if (tid == 0) {
        int b = bsel;
        thrG[c] = (b == 0) ? 0u : (u32)(0x3F000000 + (b << 16));
    }
}

// Second coalesced pass: gather all candidates with bits >= per-class threshold
// into per-class pools. Key = score_bits:~anchor_idx (score desc, idx asc on ties).
__global__ __launch_bounds__(1024)
void gather_kernel(const float4* __restrict__ cls4, const u32* __restrict__ thrG,
                   u32* __restrict__ cntG, u64* __restrict__ pool, int nvec) {
    __shared__ int thrS[C_NUM];
    int tid = threadIdx.x;
    if (tid < C_NUM) thrS[tid] = (int)thrG[tid];
    __syncthreads();
    int gid = blockIdx.x * 1024 + tid;
    const int stride = GRID_SCAN * 1024;
    const int dA = (stride * 4) / C_NUM;
    const int dC = (stride * 4) % C_NUM;
    int base = gid * 4;
    int aa0 = base / C_NUM;
    int c0 = base - aa0 * C_NUM;
    for (int v = gid; v < nvec; v += stride) {
        float4 f = cls4[v];
        float e[4] = {f.x, f.y, f.z, f.w};
        int cc = c0, aa = aa0;
#pragma unroll
        for (int k = 0; k < 4; ++k) {
            int bits = (int)__float_as_uint(e[k]);
            if (bits >= thrS[cc]) {
                u32 p = atomicAdd(&cntG[cc], 1u);
                if (p < CAP)
                    pool[(size_t)cc * CAP + p] =
                        ((u64)(u32)bits << 32) | (u64)(u32)(~(u32)aa);
            }
            cc++; if (cc == C_NUM) { cc = 0; aa++; }
        }
        c0 += dC;
        if (c0 >= C_NUM) { c0 -= C_NUM; aa0 += dA + 1; } else aa0 += dA;
    }
}

// One block per class: rank-sort candidates -> decode top-1000 -> LDS suppression
// bit-matrix -> sequential greedy NMS (wave 0, LDS-pipelined) -> final output.
__global__ __launch_bounds__(1024)
void fused_kernel(const u64* __restrict__ pool, const u32* __restrict__ cntG,
                  const float* __restrict__ anchors, const float* __restrict__ regs,
                  const int* __restrict__ imh, const int* __restrict__ imw,
                  float* __restrict__ out) {
#pragma clang fp contract(off)
    __shared__ u64 sortedK[1024];            //  8 KB
    __shared__ float4 boxLds[TOPK];          // 16 KB
    __shared__ float areaLds[TOPK];          //  4 KB
    __shared__ u64 supLds[TOPK * 16];        // 128 KB (front 16 KB aliased as key pool)
    __shared__ u64 keepI[16];
    __shared__ u64 keepF[16];

    int c = blockIdx.x, tid = threadIdx.x;
    int lane = tid & 63, wave = tid >> 6;
    u64* keysLds = (u64*)supLds;

    int n = (int)cntG[c]; if (n > CAP) n = CAP;
    for (int i = tid; i < n; i += 1024) keysLds[i] = pool[(size_t)c * CAP + i];
    sortedK[tid] = 0ull;
    __syncthreads();

    // rank-sort: rank = # keys strictly greater (keys distinct via ~idx)
    u64 k0 = (tid < n) ? keysLds[tid] : 0ull;
    u64 k1 = (tid + 1024 < n) ? keysLds[tid + 1024] : 0ull;
    int r0 = 0, r1 = 0;
    for (int j = 0; j < n; ++j) {
        u64 kj = keysLds[j];                 // wave-uniform -> LDS broadcast
        r0 += (kj > k0);
        r1 += (kj > k1);
    }
    __syncthreads();
    if (tid < n && r0 < TOPK) sortedK[r0] = k0;
    if (tid + 1024 < n && r1 < TOPK) sortedK[r1] = k1;
    __syncthreads();

    // decode top-1000
    float fw = (float)(*imw), fh = (float)(*imh);
    bool valid = false;
    if (tid < TOPK) {
        u64 key = sortedK[tid];
        float sc = __uint_as_float((u32)(key >> 32));
        int a = (int)(~(u32)key);
        valid = sc > SCORE_THR;
        float4 bx = make_float4(0.f, 0.f, 0.f, 0.f);
        if (valid) decode_box(anchors, regs, a, fw, fh, &bx);
        boxLds[tid] = bx;
        areaLds[tid] = fmaxf(bx.z - bx.x, 0.0f) * fmaxf(bx.w - bx.y, 0.0f);
    }
    u64 mb = __ballot(valid);
    if (lane == 0) keepI[wave] = mb;
    __syncthreads();                          // boxes ready; keys dead -> sup writable

    // suppression bit-matrix: bit j of row i set iff j>i && iou>0.5
    for (int i = wave; i < TOPK; i += 16) {
        float4 bi = boxLds[i];
        float ai = areaLds[i];
        int jw0 = i >> 6;
        if (lane < jw0) supLds[i * 16 + lane] = 0ull;
        for (int jw = jw0; jw < 16; ++jw) {
            int j = (jw << 6) | lane;
            bool sup = false;
            if (j > i && j < TOPK) {
                float4 bj = boxLds[j];
                float ltx = fmaxf(bi.x, bj.x), lty = fmaxf(bi.y, bj.y);
                float rbx = fminf(bi.z, bj.z), rby = fminf(bi.w, bj.w);
                float ww = fmaxf(rbx - ltx, 0.0f), hh = fmaxf(rby - lty, 0.0f);
                float inter = ww * hh;
                float uni = (ai + areaLds[j]) - inter;
                sup = (inter / fmaxf(uni, 1e-8f)) > IOU_THR;
            }
            u64 mm = __ballot(sup);
            if (lane == 0) supLds[i * 16 + jw] = mm;
        }
    }
    __syncthreads();

    // greedy NMS, wave 0, 8-deep LDS prefetch pipeline
    if (wave == 0) {
        u64 kw = (lane < 16) ? keepI[lane] : 0ull;
        u64 buf[8];
#pragma unroll
        for (int u = 0; u < 8; ++u)
            buf[u] = (lane < 16) ? supLds[u * 16 + lane] : 0ull;
        for (int i0 = 0; i0 < TOPK; i0 += 8) {
#pragma unroll
            for (int u = 0; u < 8; ++u) {
                int i = i0 + u;
                u64 word = __shfl(kw, i >> 6);
                if ((word >> (i & 63)) & 1ull) kw &= ~buf[u];
                int nx = i + 8;
                buf[u] = (nx < TOPK && lane < 16) ? supLds[nx * 16 + lane] : 0ull;
            }
        }
        if (lane < 16) keepF[lane] = kw;
    }
    __syncthreads();

    // output
    if (tid < TOPK) {
        bool keep = (keepF[tid >> 6] >> (tid & 63)) & 1ull;
        u64 key = sortedK[tid];
        float sc = __uint_as_float((u32)(key >> 32));
        int g = c * TOPK + tid;
        out[g] = keep ? sc : 0.0f;
        out[C_NUM * TOPK + g] = keep ? (float)c : -1.0f;
        float4 b = keep ? boxLds[tid] : make_float4(0.f, 0.f, 0.f, 0.f);
        ((float4*)(out + 2 * C_NUM * TOPK))[g] = b;
    }
}

extern "C" void kernel_launch(void* const* d_in, const int* in_sizes, int n_in,
                              void* d_out, int out_size, void* d_ws, size_t ws_size,
                              hipStream_t stream) {
    const float* cls  = (const float*)d_in[0];
    const float* reg  = (const float*)d_in[1];
    const float* anch = (const float*)d_in[2];
    const int* imh    = (const int*)d_in[3];
    const int* imw    = (const int*)d_in[4];
    int A = in_sizes[2] / 4;
    int nvec = (A * C_NUM) / 4;

    char* w = (char*)d_ws;
    size_t off = 0;
    auto alloc = [&](size_t bytes) -> void* {
        off = (off + 255) & ~(size_t)255;
        void* p = w + off;
        off += bytes;
        return p;
    };
    u32* histG = (u32*)alloc((size_t)C_NUM * HB * 4);
    u32* thrG  = (u32*)alloc((size_t)C_NUM * 4);
    u32* cntG  = (u32*)alloc((size_t)C_NUM * 4);
    u64* pool  = (u64*)alloc((size_t)C_NUM * CAP * 8);

    zero_kernel<<<(C_NUM * HB + 255) / 256, 256, 0, stream>>>(histG, cntG);
    hist_kernel<<<GRID_SCAN, 1024, 0, stream>>>((const float4*)cls, histG, nvec);
    thr_kernel<<<C_NUM, HB, 0, stream>>>(histG, thrG);
    gather_kernel<<<GRID_SCAN, 1024, 0, stream>>>((const float4*)cls, thrG, cntG, pool, nvec);
    fused_kernel<<<C_NUM, 1024, 0, stream>>>(pool, cntG, anch, reg, imh, imw, (float*)d_out);
}

// Round 3
// 253.062 us; speedup vs baseline: 3.0208x; 3.0208x over previous
//
#include <hip/hip_runtime.h>
#include <hip/hip_bf16.h>
#include <math.h>

typedef unsigned long long u64;
typedef unsigned int u32;

#define C_NUM 80
#define TOPK 1000
#define CAP 2048
#define HB 128
#define STG 32
#define SCORE_THR 0.05f
#define IOU_THR 0.5f
#define GRID_SCAN 256

// correctly-rounded-ish f32 exp via double (matched reference bit-exact rounds 1-2)
__device__ __forceinline__ float exp_cr(float x) {
    return (float)exp((double)x);
}

// Exact f32 replication of reference decode + clip (no FMA contraction).
__device__ __forceinline__ void decode_box(const float* __restrict__ anch,
                                           const float* __restrict__ reg,
                                           int a, float fw, float fh, float4* out) {
#pragma clang fp contract(off)
    float a0 = anch[(size_t)a * 4 + 0], a1 = anch[(size_t)a * 4 + 1];
    float a2 = anch[(size_t)a * 4 + 2], a3 = anch[(size_t)a * 4 + 3];
    float d0 = reg[(size_t)a * 4 + 0], d1 = reg[(size_t)a * 4 + 1];
    float d2 = reg[(size_t)a * 4 + 2], d3 = reg[(size_t)a * 4 + 3];
    float w = a2 - a0, h = a3 - a1;
    float cx = a0 + 0.5f * w, cy = a1 + 0.5f * h;
    float dx = d0 * 0.1f, dy = d1 * 0.1f, dw = d2 * 0.2f, dh = d3 * 0.2f;
    float t1 = dx * w; float pcx = cx + t1;
    float t2 = dy * h; float pcy = cy + t2;
    float pw = exp_cr(dw) * w;
    float ph = exp_cr(dh) * h;
    float x1 = pcx - 0.5f * pw, y1 = pcy - 0.5f * ph;
    float x2 = pcx + 0.5f * pw, y2 = pcy + 0.5f * ph;
    x1 = fminf(fmaxf(x1, 0.0f), fw);
    y1 = fminf(fmaxf(y1, 0.0f), fh);
    x2 = fminf(fmaxf(x2, 0.0f), fw);
    y2 = fminf(fmaxf(y2, 0.0f), fh);
    *out = make_float4(x1, y1, x2, y2);
}

// Per-block private histogram slices; no global atomics at all.
// slices layout: [block][C_NUM*HB], block-coalesced write.
__global__ __launch_bounds__(1024)
void hist_kernel(const float4* __restrict__ cls4, u32* __restrict__ slices, int nvec) {
    __shared__ u32 h[C_NUM * HB];                 // 40 KB
    int tid = threadIdx.x;
    for (int i = tid; i < C_NUM * HB; i += 1024) h[i] = 0u;
    __syncthreads();
    int gid = blockIdx.x * 1024 + tid;
    const int stride = GRID_SCAN * 1024;          // float4 units
    const int dC = (stride * 4) % C_NUM;
    int c0 = (gid * 4) % C_NUM;
    for (int v = gid; v < nvec; v += stride) {
        float4 f = cls4[v];
        float e[4] = {f.x, f.y, f.z, f.w};
        int cc = c0;
#pragma unroll
        for (int k = 0; k < 4; ++k) {
            int t = (((int)__float_as_uint(e[k])) - 0x3F000000) >> 16;
            if (t > 0) {
                t = t > HB - 1 ? HB - 1 : t;
                atomicAdd(&h[cc * HB + t], 1u);   // LDS atomic only
            }
            cc++; if (cc == C_NUM) cc = 0;
        }
        c0 += dC; if (c0 >= C_NUM) c0 -= C_NUM;
    }
    __syncthreads();
    u32* my = slices + (size_t)blockIdx.x * (C_NUM * HB);
    for (int i = tid; i < C_NUM * HB; i += 1024) my[i] = h[i];
}

// Per-class: reduce 256 slices (coalesced) -> suffix-sum -> threshold bit-edge.
__global__ __launch_bounds__(HB)
void thr_kernel(const u32* __restrict__ slices, u32* __restrict__ thrG) {
    __shared__ u32 s[HB];
    __shared__ int bsel;
    int c = blockIdx.x, tid = threadIdx.x;
    if (tid == 0) bsel = 0;
    u32 sum = 0;
    const u32* base = slices + c * HB + tid;
    for (int sl = 0; sl < GRID_SCAN; ++sl)
        sum += base[(size_t)sl * (C_NUM * HB)];   // lanes read consecutive -> coalesced
    s[tid] = sum;
    __syncthreads();
    for (int d = 1; d < HB; d <<= 1) {
        u32 v = s[tid] + ((tid + d < HB) ? s[tid + d] : 0u);
        __syncthreads();
        s[tid] = v;
        __syncthreads();
    }
    u32 me = s[tid];
    u32 nxt = (tid < HB - 1) ? s[tid + 1] : 0u;
    if (me >= (u32)TOPK && (tid == HB - 1 || nxt < (u32)TOPK)) bsel = tid;
    __syncthreads();
    if (tid == 0) {
        int b = bsel;
        thrG[c] = (b == 0) ? 0u : (u32)(0x3F000000 + (b << 16));
    }
}

// Gather with block-local LDS staging; ONE bulk reservation atomic per (class,block).
__global__ __launch_bounds__(1024)
void gather_kernel(const float4* __restrict__ cls4, const u32* __restrict__ thrG,
                   u32* __restrict__ cntG, u64* __restrict__ pool, int nvec) {
    __shared__ int thrS[C_NUM];
    __shared__ u32 lcnt[C_NUM];
    __shared__ u32 lbase[C_NUM];
    __shared__ u64 stage[C_NUM * STG];            // 20 KB
    int tid = threadIdx.x;
    if (tid < C_NUM) { thrS[tid] = (int)thrG[tid]; lcnt[tid] = 0u; }
    __syncthreads();

    int gid = blockIdx.x * 1024 + tid;
    const int stride = GRID_SCAN * 1024;
    const int dA = (stride * 4) / C_NUM;
    const int dC = (stride * 4) % C_NUM;
    int base = gid * 4;
    int aa0 = base / C_NUM;
    int c0 = base - aa0 * C_NUM;
    for (int v = gid; v < nvec; v += stride) {
        float4 f = cls4[v];
        float e[4] = {f.x, f.y, f.z, f.w};
        int cc = c0, aa = aa0;
#pragma unroll
        for (int k = 0; k < 4; ++k) {
            int bits = (int)__float_as_uint(e[k]);
            if (bits >= thrS[cc]) {
                u64 key = ((u64)(u32)bits << 32) | (u64)(u32)(~(u32)aa);
                u32 p = atomicAdd(&lcnt[cc], 1u);             // LDS atomic
                if (p < STG) stage[cc * STG + p] = key;
                else {                                         // rare overflow fallback
                    u32 q = atomicAdd(&cntG[cc], 1u);
                    if (q < CAP) pool[(size_t)cc * CAP + q] = key;
                }
            }
            cc++; if (cc == C_NUM) { cc = 0; aa++; }
        }
        c0 += dC;
        if (c0 >= C_NUM) { c0 -= C_NUM; aa0 += dA + 1; } else aa0 += dA;
    }
    __syncthreads();
    if (tid < C_NUM) {
        u32 nl = lcnt[tid]; if (nl > STG) nl = STG;
        lbase[tid] = nl ? atomicAdd(&cntG[tid], nl) : 0u;      // one atomic per class
        lcnt[tid] = nl;
    }
    __syncthreads();
    for (int i = tid; i < C_NUM * STG; i += 1024) {
        int c = i >> 5, k = i & (STG - 1);
        if ((u32)k < lcnt[c]) {
            u32 q = lbase[c] + (u32)k;
            if (q < CAP) pool[(size_t)c * CAP + q] = stage[i];
        }
    }
}

// One block per class: rank-sort (unrolled LDS broadcast) -> decode top-1000 -> write.
__global__ __launch_bounds__(1024)
void sortdec_kernel(const u64* __restrict__ pool, const u32* __restrict__ cntG,
                    const float* __restrict__ anchors, const float* __restrict__ regs,
                    const int* __restrict__ imh, const int* __restrict__ imw,
                    u64* __restrict__ sortedKey, float4* __restrict__ candBox,
                    float* __restrict__ candArea, u64* __restrict__ keepInit) {
    __shared__ u64 keys[CAP];                     // 16 KB
    __shared__ u64 sortedK[1024];                 //  8 KB
    int c = blockIdx.x, tid = threadIdx.x;
    int n = (int)cntG[c]; if (n > CAP) n = CAP;
    for (int i = tid; i < n; i += 1024) keys[i] = pool[(size_t)c * CAP + i];
    sortedK[tid] = 0ull;
    __syncthreads();

    u64 k0 = (tid < n) ? keys[tid] : 0ull;
    u64 k1 = (tid + 1024 < n) ? keys[tid + 1024] : 0ull;
    int r0 = 0, r1 = 0;
    int j = 0;
    for (; j + 8 <= n; j += 8) {
        u64 t0 = keys[j], t1 = keys[j + 1], t2 = keys[j + 2], t3 = keys[j + 3];
        u64 t4 = keys[j + 4], t5 = keys[j + 5], t6 = keys[j + 6], t7 = keys[j + 7];
        r0 += (t0 > k0) + (t1 > k0) + (t2 > k0) + (t3 > k0)
            + (t4 > k0) + (t5 > k0) + (t6 > k0) + (t7 > k0);
        r1 += (t0 > k1) + (t1 > k1) + (t2 > k1) + (t3 > k1)
            + (t4 > k1) + (t5 > k1) + (t6 > k1) + (t7 > k1);
    }
    for (; j < n; ++j) { u64 t = keys[j]; r0 += (t > k0); r1 += (t > k1); }
    __syncthreads();
    if (tid < n && r0 < TOPK) sortedK[r0] = k0;
    if (tid + 1024 < n && r1 < TOPK) sortedK[r1] = k1;
    __syncthreads();

    float fw = (float)(*imw), fh = (float)(*imh);
    bool valid = false;
    if (tid < TOPK) {
        u64 key = sortedK[tid];
        float sc = __uint_as_float((u32)(key >> 32));
        int a = (int)(~(u32)key);
        valid = sc > SCORE_THR;
        float4 bx = make_float4(0.f, 0.f, 0.f, 0.f);
        if (valid) decode_box(anchors, regs, a, fw, fh, &bx);
        sortedKey[(size_t)c * TOPK + tid] = key;
        candBox[(size_t)c * TOPK + tid] = bx;
        candArea[(size_t)c * TOPK + tid] =
            fmaxf(bx.z - bx.x, 0.0f) * fmaxf(bx.w - bx.y, 0.0f);
    }
    u64 mb = __ballot(valid);
    if ((tid & 63) == 0) keepInit[c * 16 + (tid >> 6)] = mb;
}

// Suppression bit-matrix, triangular, rows interleaved mod 8 for load balance.
// grid (C_NUM, 8) x 512.
__global__ __launch_bounds__(512)
void iou_kernel(const float4* __restrict__ candBox, const float* __restrict__ candArea,
                u64* __restrict__ supW) {
#pragma clang fp contract(off)
    __shared__ float4 box[TOPK];                  // 16 KB
    __shared__ float area[TOPK];                  //  4 KB
    int c = blockIdx.x, q = blockIdx.y;
    int tid = threadIdx.x, lane = tid & 63, wave = tid >> 6;
    for (int i = tid; i < TOPK; i += 512) {
        box[i] = candBox[(size_t)c * TOPK + i];
        area[i] = candArea[(size_t)c * TOPK + i];
    }
    __syncthreads();
    for (int t = wave; t < TOPK / 8; t += 8) {
        int i = q + 8 * t;
        float4 bi = box[i];
        float ai = area[i];
        int jw0 = i >> 6;
        u64* supRow = supW + ((size_t)c * TOPK + i) * 16;
        if (lane < jw0) supRow[lane] = 0ull;
        for (int jw = jw0; jw < 16; ++jw) {
            int j = (jw << 6) | lane;
            bool sup = false;
            if (j > i && j < TOPK) {
                float4 bj = box[j];
                float ltx = fmaxf(bi.x, bj.x), lty = fmaxf(bi.y, bj.y);
                float rbx = fminf(bi.z, bj.z), rby = fminf(bi.w, bj.w);
                float ww = fmaxf(rbx - ltx, 0.0f), hh = fmaxf(rby - lty, 0.0f);
                float inter = ww * hh;
                float uni = (ai + area[j]) - inter;
                sup = (inter / fmaxf(uni, 1e-8f)) > IOU_THR;
            }
            u64 mm = __ballot(sup);
            if (lane == 0) supRow[jw] = mm;
        }
    }
}

// One wave per class: sequential greedy over sup rows (8-deep prefetch), then output.
__global__ __launch_bounds__(64)
void nmsout_kernel(const u64* __restrict__ supW, const u64* __restrict__ keepInit,
                   const u64* __restrict__ sortedKey, const float4* __restrict__ candBox,
                   float* __restrict__ out) {
    int c = blockIdx.x, lane = threadIdx.x;
    const u64* rows = supW + (size_t)c * TOPK * 16;
    u64 kw = (lane < 16) ? keepInit[c * 16 + lane] : 0ull;
    u64 buf[8];
#pragma unroll
    for (int u = 0; u < 8; ++u)
        buf[u] = (lane < 16) ? rows[(size_t)u * 16 + lane] : 0ull;
    for (int i0 = 0; i0 < TOPK; i0 += 8) {
#pragma unroll
        for (int u = 0; u < 8; ++u) {
            int i = i0 + u;
            u64 word = __shfl(kw, i >> 6);
            if ((word >> (i & 63)) & 1ull) kw &= ~buf[u];
            int nx = i + 8;
            buf[u] = (nx < TOPK && lane < 16) ? rows[(size_t)nx * 16 + lane] : 0ull;
        }
    }
    // output: 16 iterations, word it lives on lane it
    for (int it = 0; it < 16; ++it) {
        int k = (it << 6) | lane;
        u64 word = __shfl(kw, it);
        if (k < TOPK) {
            bool keep = (word >> lane) & 1ull;
            int g = c * TOPK + k;
            u64 key = sortedKey[g];
            float sc = __uint_as_float((u32)(key >> 32));
            out[g] = keep ? sc : 0.0f;
            out[C_NUM * TOPK + g] = keep ? (float)c : -1.0f;
            float4 b = keep ? candBox[g] : make_float4(0.f, 0.f, 0.f, 0.f);
            ((float4*)(out + 2 * C_NUM * TOPK))[g] = b;
        }
    }
}

extern "C" void kernel_launch(void* const* d_in, const int* in_sizes, int n_in,
                              void* d_out, int out_size, void* d_ws, size_t ws_size,
                              hipStream_t stream) {
    const float* cls  = (const float*)d_in[0];
    const float* reg  = (const float*)d_in[1];
    const float* anch = (const float*)d_in[2];
    const int* imh    = (const int*)d_in[3];
    const int* imw    = (const int*)d_in[4];
    int A = in_sizes[2] / 4;
    int nvec = (A * C_NUM) / 4;

    char* w = (char*)d_ws;
    size_t off = 0;
    auto alloc = [&](size_t bytes) -> void* {
        off = (off + 255) & ~(size_t)255;
        void* p = w + off;
        off += bytes;
        return p;
    };
    u32*    cntG      = (u32*)   alloc((size_t)C_NUM * 4);
    u32*    thrG      = (u32*)   alloc((size_t)C_NUM * 4);
    u32*    slices    = (u32*)   alloc((size_t)GRID_SCAN * C_NUM * HB * 4);   // 10.5 MB
    u64*    pool      = (u64*)   alloc((size_t)C_NUM * CAP * 8);              // 1.3 MB
    u64*    sortedKey = (u64*)   alloc((size_t)C_NUM * TOPK * 8);
    float4* candBox   = (float4*)alloc((size_t)C_NUM * TOPK * 16);
    float*  candArea  = (float*) alloc((size_t)C_NUM * TOPK * 4);
    u64*    keepInit  = (u64*)   alloc((size_t)C_NUM * 16 * 8);
    u64*    supW      = (u64*)   alloc((size_t)C_NUM * TOPK * 16 * 8);        // 10.2 MB

    hipMemsetAsync(cntG, 0, (size_t)C_NUM * 4, stream);
    hist_kernel<<<GRID_SCAN, 1024, 0, stream>>>((const float4*)cls, slices, nvec);
    thr_kernel<<<C_NUM, HB, 0, stream>>>(slices, thrG);
    gather_kernel<<<GRID_SCAN, 1024, 0, stream>>>((const float4*)cls, thrG, cntG, pool, nvec);
    sortdec_kernel<<<C_NUM, 1024, 0, stream>>>(pool, cntG, anch, reg, imh, imw,
                                               sortedKey, candBox, candArea, keepInit);
    iou_kernel<<<dim3(C_NUM, 8), 512, 0, stream>>>(candBox, candArea, supW);
    nmsout_kernel<<<C_NUM, 64, 0, stream>>>(supW, keepInit, sortedKey, candBox,
                                            (float*)d_out);
}

// Round 4
// 213.310 us; speedup vs baseline: 3.5837x; 1.1864x over previous
//
#include <hip/hip_runtime.h>
#include <hip/hip_bf16.h>
#include <math.h>

typedef unsigned long long u64;
typedef unsigned int u32;

#define C_NUM 80
#define TOPK 1000
#define CAP 2048
#define HB 128
#define STG 32
#define SCORE_THR 0.05f
#define IOU_THR 0.5f
#define GRID_SCAN 256

// correctly-rounded-ish f32 exp via double (matched reference bit-exact rounds 1-3)
__device__ __forceinline__ float exp_cr(float x) {
    return (float)exp((double)x);
}

// Exact f32 replication of reference decode + clip (no FMA contraction).
__device__ __forceinline__ void decode_box(const float* __restrict__ anch,
                                           const float* __restrict__ reg,
                                           int a, float fw, float fh, float4* out) {
#pragma clang fp contract(off)
    float a0 = anch[(size_t)a * 4 + 0], a1 = anch[(size_t)a * 4 + 1];
    float a2 = anch[(size_t)a * 4 + 2], a3 = anch[(size_t)a * 4 + 3];
    float d0 = reg[(size_t)a * 4 + 0], d1 = reg[(size_t)a * 4 + 1];
    float d2 = reg[(size_t)a * 4 + 2], d3 = reg[(size_t)a * 4 + 3];
    float w = a2 - a0, h = a3 - a1;
    float cx = a0 + 0.5f * w, cy = a1 + 0.5f * h;
    float dx = d0 * 0.1f, dy = d1 * 0.1f, dw = d2 * 0.2f, dh = d3 * 0.2f;
    float t1 = dx * w; float pcx = cx + t1;
    float t2 = dy * h; float pcy = cy + t2;
    float pw = exp_cr(dw) * w;
    float ph = exp_cr(dh) * h;
    float x1 = pcx - 0.5f * pw, y1 = pcy - 0.5f * ph;
    float x2 = pcx + 0.5f * pw, y2 = pcy + 0.5f * ph;
    x1 = fminf(fmaxf(x1, 0.0f), fw);
    y1 = fminf(fmaxf(y1, 0.0f), fh);
    x2 = fminf(fmaxf(x2, 0.0f), fw);
    y2 = fminf(fmaxf(y2, 0.0f), fh);
    *out = make_float4(x1, y1, x2, y2);
}

// Per-block private histogram slices; no global atomics at all.
__global__ __launch_bounds__(1024)
void hist_kernel(const float4* __restrict__ cls4, u32* __restrict__ slices, int nvec) {
    __shared__ u32 h[C_NUM * HB];                 // 40 KB
    int tid = threadIdx.x;
    for (int i = tid; i < C_NUM * HB; i += 1024) h[i] = 0u;
    __syncthreads();
    int gid = blockIdx.x * 1024 + tid;
    const int stride = GRID_SCAN * 1024;          // float4 units
    const int dC = (stride * 4) % C_NUM;
    int c0 = (gid * 4) % C_NUM;
    for (int v = gid; v < nvec; v += stride) {
        float4 f = cls4[v];
        float e[4] = {f.x, f.y, f.z, f.w};
        int cc = c0;
#pragma unroll
        for (int k = 0; k < 4; ++k) {
            int t = (((int)__float_as_uint(e[k])) - 0x3F000000) >> 16;
            if (t > 0) {
                t = t > HB - 1 ? HB - 1 : t;
                atomicAdd(&h[cc * HB + t], 1u);   // LDS atomic only
            }
            cc++; if (cc == C_NUM) cc = 0;
        }
        c0 += dC; if (c0 >= C_NUM) c0 -= C_NUM;
    }
    __syncthreads();
    u32* my = slices + (size_t)blockIdx.x * (C_NUM * HB);
    for (int i = tid; i < C_NUM * HB; i += 1024) my[i] = h[i];
}

// Per-class: parallel reduce of 256 slices (8 groups x 128 buckets) -> suffix-sum
// -> threshold bit-edge.
__global__ __launch_bounds__(1024)
void thr_kernel(const u32* __restrict__ slices, u32* __restrict__ thrG) {
    __shared__ u32 part[8][HB];
    __shared__ u32 s[HB];
    __shared__ int bsel;
    int c = blockIdx.x, tid = threadIdx.x;
    int b = tid & (HB - 1), g = tid >> 7;         // 8 groups of 32 slices each
    u32 sum = 0;
    const u32* base = slices + c * HB + b;
    for (int sl = g * 32; sl < g * 32 + 32; ++sl)
        sum += base[(size_t)sl * (C_NUM * HB)];   // lanes read consecutive -> coalesced
    part[g][b] = sum;
    if (tid == 0) bsel = 0;
    __syncthreads();
    if (tid < HB) {
        u32 t = 0;
#pragma unroll
        for (int g2 = 0; g2 < 8; ++g2) t += part[g2][tid];
        s[tid] = t;
    }
    __syncthreads();
    for (int d = 1; d < HB; d <<= 1) {
        u32 v = 0;
        if (tid < HB) v = s[tid] + ((tid + d < HB) ? s[tid + d] : 0u);
        __syncthreads();
        if (tid < HB) s[tid] = v;
        __syncthreads();
    }
    if (tid < HB) {
        u32 me = s[tid];
        u32 nxt = (tid < HB - 1) ? s[tid + 1] : 0u;
        if (me >= (u32)TOPK && (tid == HB - 1 || nxt < (u32)TOPK)) bsel = tid;
    }
    __syncthreads();
    if (tid == 0) {
        int bb = bsel;
        thrG[c] = (bb == 0) ? 0u : (u32)(0x3F000000 + (bb << 16));
    }
}

// Gather with block-local LDS staging; ONE bulk reservation atomic per (class,block).
__global__ __launch_bounds__(1024)
void gather_kernel(const float4* __restrict__ cls4, const u32* __restrict__ thrG,
                   u32* __restrict__ cntG, u64* __restrict__ pool, int nvec) {
    __shared__ int thrS[C_NUM];
    __shared__ u32 lcnt[C_NUM];
    __shared__ u32 lbase[C_NUM];
    __shared__ u64 stage[C_NUM * STG];            // 20 KB
    int tid = threadIdx.x;
    if (tid < C_NUM) { thrS[tid] = (int)thrG[tid]; lcnt[tid] = 0u; }
    __syncthreads();

    int gid = blockIdx.x * 1024 + tid;
    const int stride = GRID_SCAN * 1024;
    const int dA = (stride * 4) / C_NUM;
    const int dC = (stride * 4) % C_NUM;
    int base = gid * 4;
    int aa0 = base / C_NUM;
    int c0 = base - aa0 * C_NUM;
    for (int v = gid; v < nvec; v += stride) {
        float4 f = cls4[v];
        float e[4] = {f.x, f.y, f.z, f.w};
        int cc = c0, aa = aa0;
#pragma unroll
        for (int k = 0; k < 4; ++k) {
            int bits = (int)__float_as_uint(e[k]);
            if (bits >= thrS[cc]) {
                u64 key = ((u64)(u32)bits << 32) | (u64)(u32)(~(u32)aa);
                u32 p = atomicAdd(&lcnt[cc], 1u);             // LDS atomic
                if (p < STG) stage[cc * STG + p] = key;
                else {                                         // rare overflow fallback
                    u32 q = atomicAdd(&cntG[cc], 1u);
                    if (q < CAP) pool[(size_t)cc * CAP + q] = key;
                }
            }
            cc++; if (cc == C_NUM) { cc = 0; aa++; }
        }
        c0 += dC;
        if (c0 >= C_NUM) { c0 -= C_NUM; aa0 += dA + 1; } else aa0 += dA;
    }
    __syncthreads();
    if (tid < C_NUM) {
        u32 nl = lcnt[tid]; if (nl > STG) nl = STG;
        lbase[tid] = nl ? atomicAdd(&cntG[tid], nl) : 0u;      // one atomic per class
        lcnt[tid] = nl;
    }
    __syncthreads();
    for (int i = tid; i < C_NUM * STG; i += 1024) {
        int c = i >> 5, k = i & (STG - 1);
        if ((u32)k < lcnt[c]) {
            u32 q = lbase[c] + (u32)k;
            if (q < CAP) pool[(size_t)c * CAP + q] = stage[i];
        }
    }
}

// One block per class: rank-sort (unrolled LDS broadcast) -> decode top-1000 -> write.
__global__ __launch_bounds__(1024)
void sortdec_kernel(const u64* __restrict__ pool, const u32* __restrict__ cntG,
                    const float* __restrict__ anchors, const float* __restrict__ regs,
                    const int* __restrict__ imh, const int* __restrict__ imw,
                    u64* __restrict__ sortedKey, float4* __restrict__ candBox,
                    float* __restrict__ candArea, u64* __restrict__ keepInit) {
    __shared__ u64 keys[CAP];                     // 16 KB
    __shared__ u64 sortedK[1024];                 //  8 KB
    int c = blockIdx.x, tid = threadIdx.x;
    int n = (int)cntG[c]; if (n > CAP) n = CAP;
    for (int i = tid; i < n; i += 1024) keys[i] = pool[(size_t)c * CAP + i];
    sortedK[tid] = 0ull;
    __syncthreads();

    u64 k0 = (tid < n) ? keys[tid] : 0ull;
    u64 k1 = (tid + 1024 < n) ? keys[tid + 1024] : 0ull;
    int r0 = 0, r1 = 0;
    int j = 0;
    for (; j + 8 <= n; j += 8) {
        u64 t0 = keys[j], t1 = keys[j + 1], t2 = keys[j + 2], t3 = keys[j + 3];
        u64 t4 = keys[j + 4], t5 = keys[j + 5], t6 = keys[j + 6], t7 = keys[j + 7];
        r0 += (t0 > k0) + (t1 > k0) + (t2 > k0) + (t3 > k0)
            + (t4 > k0) + (t5 > k0) + (t6 > k0) + (t7 > k0);
        r1 += (t0 > k1) + (t1 > k1) + (t2 > k1) + (t3 > k1)
            + (t4 > k1) + (t5 > k1) + (t6 > k1) + (t7 > k1);
    }
    for (; j < n; ++j) { u64 t = keys[j]; r0 += (t > k0); r1 += (t > k1); }
    __syncthreads();
    if (tid < n && r0 < TOPK) sortedK[r0] = k0;
    if (tid + 1024 < n && r1 < TOPK) sortedK[r1] = k1;
    __syncthreads();

    float fw = (float)(*imw), fh = (float)(*imh);
    bool valid = false;
    if (tid < TOPK) {
        u64 key = sortedK[tid];
        float sc = __uint_as_float((u32)(key >> 32));
        int a = (int)(~(u32)key);
        valid = sc > SCORE_THR;
        float4 bx = make_float4(0.f, 0.f, 0.f, 0.f);
        if (valid) decode_box(anchors, regs, a, fw, fh, &bx);
        sortedKey[(size_t)c * TOPK + tid] = key;
        candBox[(size_t)c * TOPK + tid] = bx;
        candArea[(size_t)c * TOPK + tid] =
            fmaxf(bx.z - bx.x, 0.0f) * fmaxf(bx.w - bx.y, 0.0f);
    }
    u64 mb = __ballot(valid);
    if ((tid & 63) == 0) keepInit[c * 16 + (tid >> 6)] = mb;
}

// Suppression bit-matrix, triangular, rows interleaved mod 8 for load balance.
__global__ __launch_bounds__(512)
void iou_kernel(const float4* __restrict__ candBox, const float* __restrict__ candArea,
                u64* __restrict__ supW) {
#pragma clang fp contract(off)
    __shared__ float4 box[TOPK];                  // 16 KB
    __shared__ float area[TOPK];                  //  4 KB
    int c = blockIdx.x, q = blockIdx.y;
    int tid = threadIdx.x, lane = tid & 63, wave = tid >> 6;
    for (int i = tid; i < TOPK; i += 512) {
        box[i] = candBox[(size_t)c * TOPK + i];
        area[i] = candArea[(size_t)c * TOPK + i];
    }
    __syncthreads();
    for (int t = wave; t < TOPK / 8; t += 8) {
        int i = q + 8 * t;
        float4 bi = box[i];
        float ai = area[i];
        int jw0 = i >> 6;
        u64* supRow = supW + ((size_t)c * TOPK + i) * 16;
        if (lane < jw0) supRow[lane] = 0ull;
        for (int jw = jw0; jw < 16; ++jw) {
            int j = (jw << 6) | lane;
            bool sup = false;
            if (j > i && j < TOPK) {
                float4 bj = box[j];
                float ltx = fmaxf(bi.x, bj.x), lty = fmaxf(bi.y, bj.y);
                float rbx = fminf(bi.z, bj.z), rby = fminf(bi.w, bj.w);
                float ww = fmaxf(rbx - ltx, 0.0f), hh = fmaxf(rby - lty, 0.0f);
                float inter = ww * hh;
                float uni = (ai + area[j]) - inter;
                sup = (inter / fmaxf(uni, 1e-8f)) > IOU_THR;
            }
            u64 mm = __ballot(sup);
            if (lane == 0) supRow[jw] = mm;
        }
    }
}

// 1024 threads/class: 16 waves bulk-copy sup matrix (128 KB) into LDS, wave 0 runs
// the greedy pass with readlane (uniform-lane broadcast, SALU-side) in the chain,
// then all threads write the output coalesced.
__global__ __launch_bounds__(1024)
void nmsout_kernel(const u64* __restrict__ supW, const u64* __restrict__ keepInit,
                   const u64* __restrict__ sortedKey, const float4* __restrict__ candBox,
                   float* __restrict__ out) {
    __shared__ __align__(16) u64 supLds[TOPK * 16];   // 128 KB
    __shared__ u64 keepF[16];
    int c = blockIdx.x, tid = threadIdx.x;

    const float4* src = (const float4*)(supW + (size_t)c * TOPK * 16);
    float4* dst = (float4*)supLds;
    for (int i = tid; i < TOPK * 8; i += 1024) dst[i] = src[i];
    __syncthreads();

    if (tid < 64) {
        int lane = tid;
        u64 kw = (lane < 16) ? keepInit[c * 16 + lane] : 0ull;
        u64 buf[8];
#pragma unroll
        for (int u = 0; u < 8; ++u)
            buf[u] = (lane < 16) ? supLds[u * 16 + lane] : 0ull;
        for (int i0 = 0; i0 < TOPK; i0 += 8) {
#pragma unroll
            for (int u = 0; u < 8; ++u) {
                int i = i0 + u;
                u32 wlo = (u32)__builtin_amdgcn_readlane((int)(u32)kw, i >> 6);
                u32 whi = (u32)__builtin_amdgcn_readlane((int)(u32)(kw >> 32), i >> 6);
                u32 sel = (i & 32) ? whi : wlo;
                u64 m = (u64)0 - (u64)((sel >> (i & 31)) & 1u);
                kw &= ~(buf[u] & m);
                int nx = i + 8;
                buf[u] = (nx < TOPK && lane < 16) ? supLds[nx * 16 + lane] : 0ull;
            }
        }
        if (lane < 16) keepF[lane] = kw;
    }
    __syncthreads();

    if (tid < TOPK) {
        bool keep = (keepF[tid >> 6] >> (tid & 63)) & 1ull;
        int g = c * TOPK + tid;
        u64 key = sortedKey[g];
        float sc = __uint_as_float((u32)(key >> 32));
        out[g] = keep ? sc : 0.0f;
        out[C_NUM * TOPK + g] = keep ? (float)c : -1.0f;
        float4 b = keep ? candBox[g] : make_float4(0.f, 0.f, 0.f, 0.f);
        ((float4*)(out + 2 * C_NUM * TOPK))[g] = b;
    }
}

extern "C" void kernel_launch(void* const* d_in, const int* in_sizes, int n_in,
                              void* d_out, int out_size, void* d_ws, size_t ws_size,
                              hipStream_t stream) {
    const float* cls  = (const float*)d_in[0];
    const float* reg  = (const float*)d_in[1];
    const float* anch = (const float*)d_in[2];
    const int* imh    = (const int*)d_in[3];
    const int* imw    = (const int*)d_in[4];
    int A = in_sizes[2] / 4;
    int nvec = (A * C_NUM) / 4;

    char* w = (char*)d_ws;
    size_t off = 0;
    auto alloc = [&](size_t bytes) -> void* {
        off = (off + 255) & ~(size_t)255;
        void* p = w + off;
        off += bytes;
        return p;
    };
    u32*    cntG      = (u32*)   alloc((size_t)C_NUM * 4);
    u32*    thrG      = (u32*)   alloc((size_t)C_NUM * 4);
    u32*    slices    = (u32*)   alloc((size_t)GRID_SCAN * C_NUM * HB * 4);   // 10.5 MB
    u64*    pool      = (u64*)   alloc((size_t)C_NUM * CAP * 8);              // 1.3 MB
    u64*    sortedKey = (u64*)   alloc((size_t)C_NUM * TOPK * 8);
    float4* candBox   = (float4*)alloc((size_t)C_NUM * TOPK * 16);
    float*  candArea  = (float*) alloc((size_t)C_NUM * TOPK * 4);
    u64*    keepInit  = (u64*)   alloc((size_t)C_NUM * 16 * 8);
    u64*    supW      = (u64*)   alloc((size_t)C_NUM * TOPK * 16 * 8);        // 10.2 MB

    hipMemsetAsync(cntG, 0, (size_t)C_NUM * 4, stream);
    hist_kernel<<<GRID_SCAN, 1024, 0, stream>>>((const float4*)cls, slices, nvec);
    thr_kernel<<<C_NUM, 1024, 0, stream>>>(slices, thrG);
    gather_kernel<<<GRID_SCAN, 1024, 0, stream>>>((const float4*)cls, thrG, cntG, pool, nvec);
    sortdec_kernel<<<C_NUM, 1024, 0, stream>>>(pool, cntG, anch, reg, imh, imw,
                                               sortedKey, candBox, candArea, keepInit);
    iou_kernel<<<dim3(C_NUM, 8), 512, 0, stream>>>(candBox, candArea, supW);
    nmsout_kernel<<<C_NUM, 1024, 0, stream>>>(supW, keepInit, sortedKey, candBox,
                                              (float*)d_out);
}

// Round 5
// 201.802 us; speedup vs baseline: 3.7881x; 1.0570x over previous
//
#include <hip/hip_runtime.h>
#include <hip/hip_bf16.h>
#include <math.h>

typedef unsigned long long u64;
typedef unsigned int u32;

#define C_NUM 80
#define TOPK 1000
#define CAP 2048
#define HB 128
#define STG 32
#define SCORE_THR 0.05f
#define IOU_THR 0.5f
#define GRID_SCAN 256

// correctly-rounded-ish f32 exp via double (matched reference bit-exact rounds 1-4)
__device__ __forceinline__ float exp_cr(float x) {
    return (float)exp((double)x);
}

// Exact f32 replication of reference decode + clip (no FMA contraction).
__device__ __forceinline__ void decode_box(const float* __restrict__ anch,
                                           const float* __restrict__ reg,
                                           int a, float fw, float fh, float4* out) {
#pragma clang fp contract(off)
    float a0 = anch[(size_t)a * 4 + 0], a1 = anch[(size_t)a * 4 + 1];
    float a2 = anch[(size_t)a * 4 + 2], a3 = anch[(size_t)a * 4 + 3];
    float d0 = reg[(size_t)a * 4 + 0], d1 = reg[(size_t)a * 4 + 1];
    float d2 = reg[(size_t)a * 4 + 2], d3 = reg[(size_t)a * 4 + 3];
    float w = a2 - a0, h = a3 - a1;
    float cx = a0 + 0.5f * w, cy = a1 + 0.5f * h;
    float dx = d0 * 0.1f, dy = d1 * 0.1f, dw = d2 * 0.2f, dh = d3 * 0.2f;
    float t1 = dx * w; float pcx = cx + t1;
    float t2 = dy * h; float pcy = cy + t2;
    float pw = exp_cr(dw) * w;
    float ph = exp_cr(dh) * h;
    float x1 = pcx - 0.5f * pw, y1 = pcy - 0.5f * ph;
    float x2 = pcx + 0.5f * pw, y2 = pcy + 0.5f * ph;
    x1 = fminf(fmaxf(x1, 0.0f), fw);
    y1 = fminf(fmaxf(y1, 0.0f), fh);
    x2 = fminf(fmaxf(x2, 0.0f), fw);
    y2 = fminf(fmaxf(y2, 0.0f), fh);
    *out = make_float4(x1, y1, x2, y2);
}

// Per-block private histogram slices; no global atomics at all.
__global__ __launch_bounds__(1024)
void hist_kernel(const float4* __restrict__ cls4, u32* __restrict__ slices, int nvec) {
    __shared__ u32 h[C_NUM * HB];                 // 40 KB
    int tid = threadIdx.x;
    for (int i = tid; i < C_NUM * HB; i += 1024) h[i] = 0u;
    __syncthreads();
    int gid = blockIdx.x * 1024 + tid;
    const int stride = GRID_SCAN * 1024;          // float4 units
    const int dC = (stride * 4) % C_NUM;
    int c0 = (gid * 4) % C_NUM;
    for (int v = gid; v < nvec; v += stride) {
        float4 f = cls4[v];
        float e[4] = {f.x, f.y, f.z, f.w};
        int cc = c0;
#pragma unroll
        for (int k = 0; k < 4; ++k) {
            int t = (((int)__float_as_uint(e[k])) - 0x3F000000) >> 16;
            if (t > 0) {
                t = t > HB - 1 ? HB - 1 : t;
                atomicAdd(&h[cc * HB + t], 1u);   // LDS atomic only
            }
            cc++; if (cc == C_NUM) cc = 0;
        }
        c0 += dC; if (c0 >= C_NUM) c0 -= C_NUM;
    }
    __syncthreads();
    u32* my = slices + (size_t)blockIdx.x * (C_NUM * HB);
    for (int i = tid; i < C_NUM * HB; i += 1024) my[i] = h[i];
}

// Per-class: parallel reduce of 256 slices (8 groups x 128 buckets) -> suffix-sum
// -> threshold bit-edge.
__global__ __launch_bounds__(1024)
void thr_kernel(const u32* __restrict__ slices, u32* __restrict__ thrG) {
    __shared__ u32 part[8][HB];
    __shared__ u32 s[HB];
    __shared__ int bsel;
    int c = blockIdx.x, tid = threadIdx.x;
    int b = tid & (HB - 1), g = tid >> 7;         // 8 groups of 32 slices each
    u32 sum = 0;
    const u32* base = slices + c * HB + b;
    for (int sl = g * 32; sl < g * 32 + 32; ++sl)
        sum += base[(size_t)sl * (C_NUM * HB)];   // lanes read consecutive -> coalesced
    part[g][b] = sum;
    if (tid == 0) bsel = 0;
    __syncthreads();
    if (tid < HB) {
        u32 t = 0;
#pragma unroll
        for (int g2 = 0; g2 < 8; ++g2) t += part[g2][tid];
        s[tid] = t;
    }
    __syncthreads();
    for (int d = 1; d < HB; d <<= 1) {
        u32 v = 0;
        if (tid < HB) v = s[tid] + ((tid + d < HB) ? s[tid + d] : 0u);
        __syncthreads();
        if (tid < HB) s[tid] = v;
        __syncthreads();
    }
    if (tid < HB) {
        u32 me = s[tid];
        u32 nxt = (tid < HB - 1) ? s[tid + 1] : 0u;
        if (me >= (u32)TOPK && (tid == HB - 1 || nxt < (u32)TOPK)) bsel = tid;
    }
    __syncthreads();
    if (tid == 0) {
        int bb = bsel;
        thrG[c] = (bb == 0) ? 0u : (u32)(0x3F000000 + (bb << 16));
    }
}

// Gather with block-local LDS staging; ONE bulk reservation atomic per (class,block).
__global__ __launch_bounds__(1024)
void gather_kernel(const float4* __restrict__ cls4, const u32* __restrict__ thrG,
                   u32* __restrict__ cntG, u64* __restrict__ pool, int nvec) {
    __shared__ int thrS[C_NUM];
    __shared__ u32 lcnt[C_NUM];
    __shared__ u32 lbase[C_NUM];
    __shared__ u64 stage[C_NUM * STG];            // 20 KB
    int tid = threadIdx.x;
    if (tid < C_NUM) { thrS[tid] = (int)thrG[tid]; lcnt[tid] = 0u; }
    __syncthreads();

    int gid = blockIdx.x * 1024 + tid;
    const int stride = GRID_SCAN * 1024;
    const int dA = (stride * 4) / C_NUM;
    const int dC = (stride * 4) % C_NUM;
    int base = gid * 4;
    int aa0 = base / C_NUM;
    int c0 = base - aa0 * C_NUM;
    for (int v = gid; v < nvec; v += stride) {
        float4 f = cls4[v];
        float e[4] = {f.x, f.y, f.z, f.w};
        int cc = c0, aa = aa0;
#pragma unroll
        for (int k = 0; k < 4; ++k) {
            int bits = (int)__float_as_uint(e[k]);
            if (bits >= thrS[cc]) {
                u64 key = ((u64)(u32)bits << 32) | (u64)(u32)(~(u32)aa);
                u32 p = atomicAdd(&lcnt[cc], 1u);             // LDS atomic
                if (p < STG) stage[cc * STG + p] = key;
                else {                                         // rare overflow fallback
                    u32 q = atomicAdd(&cntG[cc], 1u);
                    if (q < CAP) pool[(size_t)cc * CAP + q] = key;
                }
            }
            cc++; if (cc == C_NUM) { cc = 0; aa++; }
        }
        c0 += dC;
        if (c0 >= C_NUM) { c0 -= C_NUM; aa0 += dA + 1; } else aa0 += dA;
    }
    __syncthreads();
    if (tid < C_NUM) {
        u32 nl = lcnt[tid]; if (nl > STG) nl = STG;
        lbase[tid] = nl ? atomicAdd(&cntG[tid], nl) : 0u;      // one atomic per class
        lcnt[tid] = nl;
    }
    __syncthreads();
    for (int i = tid; i < C_NUM * STG; i += 1024) {
        int c = i >> 5, k = i & (STG - 1);
        if ((u32)k < lcnt[c]) {
            u32 q = lbase[c] + (u32)k;
            if (q < CAP) pool[(size_t)c * CAP + q] = stage[i];
        }
    }
}

// One block per class: rank-sort (unrolled LDS broadcast) -> decode top-1000 -> write.
__global__ __launch_bounds__(1024)
void sortdec_kernel(const u64* __restrict__ pool, const u32* __restrict__ cntG,
                    const float* __restrict__ anchors, const float* __restrict__ regs,
                    const int* __restrict__ imh, const int* __restrict__ imw,
                    u64* __restrict__ sortedKey, float4* __restrict__ candBox,
                    float* __restrict__ candArea, u64* __restrict__ keepInit) {
    __shared__ u64 keys[CAP];                     // 16 KB
    __shared__ u64 sortedK[1024];                 //  8 KB
    int c = blockIdx.x, tid = threadIdx.x;
    int n = (int)cntG[c]; if (n > CAP) n = CAP;
    for (int i = tid; i < n; i += 1024) keys[i] = pool[(size_t)c * CAP + i];
    sortedK[tid] = 0ull;
    __syncthreads();

    u64 k0 = (tid < n) ? keys[tid] : 0ull;
    u64 k1 = (tid + 1024 < n) ? keys[tid + 1024] : 0ull;
    int r0 = 0, r1 = 0;
    int j = 0;
    for (; j + 8 <= n; j += 8) {
        u64 t0 = keys[j], t1 = keys[j + 1], t2 = keys[j + 2], t3 = keys[j + 3];
        u64 t4 = keys[j + 4], t5 = keys[j + 5], t6 = keys[j + 6], t7 = keys[j + 7];
        r0 += (t0 > k0) + (t1 > k0) + (t2 > k0) + (t3 > k0)
            + (t4 > k0) + (t5 > k0) + (t6 > k0) + (t7 > k0);
        r1 += (t0 > k1) + (t1 > k1) + (t2 > k1) + (t3 > k1)
            + (t4 > k1) + (t5 > k1) + (t6 > k1) + (t7 > k1);
    }
    for (; j < n; ++j) { u64 t = keys[j]; r0 += (t > k0); r1 += (t > k1); }
    __syncthreads();
    if (tid < n && r0 < TOPK) sortedK[r0] = k0;
    if (tid + 1024 < n && r1 < TOPK) sortedK[r1] = k1;
    __syncthreads();

    float fw = (float)(*imw), fh = (float)(*imh);
    bool valid = false;
    if (tid < TOPK) {
        u64 key = sortedK[tid];
        float sc = __uint_as_float((u32)(key >> 32));
        int a = (int)(~(u32)key);
        valid = sc > SCORE_THR;
        float4 bx = make_float4(0.f, 0.f, 0.f, 0.f);
        if (valid) decode_box(anchors, regs, a, fw, fh, &bx);
        sortedKey[(size_t)c * TOPK + tid] = key;
        candBox[(size_t)c * TOPK + tid] = bx;
        candArea[(size_t)c * TOPK + tid] =
            fmaxf(bx.z - bx.x, 0.0f) * fmaxf(bx.w - bx.y, 0.0f);
    }
    u64 mb = __ballot(valid);
    if ((tid & 63) == 0) keepInit[c * 16 + (tid >> 6)] = mb;
}

// Suppression bit-matrix, triangular, rows interleaved mod 16 for load balance.
// grid (C_NUM, 16) x 256 = 1280 blocks = exactly 5 blocks/CU (LDS 5x20.25KB fits).
// Division eliminated: RN32(inter/d) > 0.5f  <=>  inter > (0.5+2^-25)*d, the RHS
// product (24-bit x 25-bit significands <= 49 bits) is EXACT in double and the tie
// point is unreachable for f32 operands -> decisions bit-identical to f32 division.
__global__ __launch_bounds__(256)
void iou_kernel(const float4* __restrict__ candBox, const float* __restrict__ candArea,
                u64* __restrict__ supW) {
#pragma clang fp contract(off)
    __shared__ float4 box[TOPK];                  // 16 KB
    __shared__ float area[TOPK];                  //  4 KB
    int c = blockIdx.x, q = blockIdx.y;
    int tid = threadIdx.x, lane = tid & 63, wave = tid >> 6;
    for (int i = tid; i < TOPK; i += 256) {
        box[i] = candBox[(size_t)c * TOPK + i];
        area[i] = candArea[(size_t)c * TOPK + i];
    }
    __syncthreads();
    const double CC = 0.5 + 0x1p-25;
    for (int t = wave; 16 * t + q < TOPK; t += 4) {
        int i = 16 * t + q;
        float4 bi = box[i];
        float ai = area[i];
        int jw0 = i >> 6;
        u64* supRow = supW + ((size_t)c * TOPK + i) * 16;
        if (lane < jw0) supRow[lane] = 0ull;
#pragma unroll 4
        for (int jw = jw0; jw < 16; ++jw) {
            int j = (jw << 6) | lane;
            bool sup = false;
            if (j > i && j < TOPK) {
                float4 bj = box[j];
                float ltx = fmaxf(bi.x, bj.x), lty = fmaxf(bi.y, bj.y);
                float rbx = fminf(bi.z, bj.z), rby = fminf(bi.w, bj.w);
                float ww = fmaxf(rbx - ltx, 0.0f), hh = fmaxf(rby - lty, 0.0f);
                float inter = ww * hh;
                float uni = (ai + area[j]) - inter;
                float d = fmaxf(uni, 1e-8f);
                sup = (double)inter > CC * (double)d;
            }
            u64 mm = __ballot(sup);
            if (lane == 0) supRow[jw] = mm;
        }
    }
}

// 1024 threads/class: 16 waves bulk-copy sup matrix (128 KB) into LDS, wave 0 runs
// the greedy pass with readlane (uniform-lane broadcast, SALU-side) in the chain,
// then all threads write the output coalesced.
__global__ __launch_bounds__(1024)
void nmsout_kernel(const u64* __restrict__ supW, const u64* __restrict__ keepInit,
                   const u64* __restrict__ sortedKey, const float4* __restrict__ candBox,
                   float* __restrict__ out) {
    __shared__ __align__(16) u64 supLds[TOPK * 16];   // 128 KB
    __shared__ u64 keepF[16];
    int c = blockIdx.x, tid = threadIdx.x;

    const float4* src = (const float4*)(supW + (size_t)c * TOPK * 16);
    float4* dst = (float4*)supLds;
    for (int i = tid; i < TOPK * 8; i += 1024) dst[i] = src[i];
    __syncthreads();

    if (tid < 64) {
        int lane = tid;
        u64 kw = (lane < 16) ? keepInit[c * 16 + lane] : 0ull;
        u64 buf[8];
#pragma unroll
        for (int u = 0; u < 8; ++u)
            buf[u] = (lane < 16) ? supLds[u * 16 + lane] : 0ull;
        for (int i0 = 0; i0 < TOPK; i0 += 8) {
#pragma unroll
            for (int u = 0; u < 8; ++u) {
                int i = i0 + u;
                u32 wlo = (u32)__builtin_amdgcn_readlane((int)(u32)kw, i >> 6);
                u32 whi = (u32)__builtin_amdgcn_readlane((int)(u32)(kw >> 32), i >> 6);
                u32 sel = (i & 32) ? whi : wlo;
                u64 m = (u64)0 - (u64)((sel >> (i & 31)) & 1u);
                kw &= ~(buf[u] & m);
                int nx = i + 8;
                buf[u] = (nx < TOPK && lane < 16) ? supLds[nx * 16 + lane] : 0ull;
            }
        }
        if (lane < 16) keepF[lane] = kw;
    }
    __syncthreads();

    if (tid < TOPK) {
        bool keep = (keepF[tid >> 6] >> (tid & 63)) & 1ull;
        int g = c * TOPK + tid;
        u64 key = sortedKey[g];
        float sc = __uint_as_float((u32)(key >> 32));
        out[g] = keep ? sc : 0.0f;
        out[C_NUM * TOPK + g] = keep ? (float)c : -1.0f;
        float4 b = keep ? candBox[g] : make_float4(0.f, 0.f, 0.f, 0.f);
        ((float4*)(out + 2 * C_NUM * TOPK))[g] = b;
    }
}

extern "C" void kernel_launch(void* const* d_in, const int* in_sizes, int n_in,
                              void* d_out, int out_size, void* d_ws, size_t ws_size,
                              hipStream_t stream) {
    const float* cls  = (const float*)d_in[0];
    const float* reg  = (const float*)d_in[1];
    const float* anch = (const float*)d_in[2];
    const int* imh    = (const int*)d_in[3];
    const int* imw    = (const int*)d_in[4];
    int A = in_sizes[2] / 4;
    int nvec = (A * C_NUM) / 4;

    char* w = (char*)d_ws;
    size_t off = 0;
    auto alloc = [&](size_t bytes) -> void* {
        off = (off + 255) & ~(size_t)255;
        void* p = w + off;
        off += bytes;
        return p;
    };
    u32*    cntG      = (u32*)   alloc((size_t)C_NUM * 4);
    u32*    thrG      = (u32*)   alloc((size_t)C_NUM * 4);
    u32*    slices    = (u32*)   alloc((size_t)GRID_SCAN * C_NUM * HB * 4);   // 10.5 MB
    u64*    pool      = (u64*)   alloc((size_t)C_NUM * CAP * 8);              // 1.3 MB
    u64*    sortedKey = (u64*)   alloc((size_t)C_NUM * TOPK * 8);
    float4* candBox   = (float4*)alloc((size_t)C_NUM * TOPK * 16);
    float*  candArea  = (float*) alloc((size_t)C_NUM * TOPK * 4);
    u64*    keepInit  = (u64*)   alloc((size_t)C_NUM * 16 * 8);
    u64*    supW      = (u64*)   alloc((size_t)C_NUM * TOPK * 16 * 8);        // 10.2 MB

    hipMemsetAsync(cntG, 0, (size_t)C_NUM * 4, stream);
    hist_kernel<<<GRID_SCAN, 1024, 0, stream>>>((const float4*)cls, slices, nvec);
    thr_kernel<<<C_NUM, 1024, 0, stream>>>(slices, thrG);
    gather_kernel<<<GRID_SCAN, 1024, 0, stream>>>((const float4*)cls, thrG, cntG, pool, nvec);
    sortdec_kernel<<<C_NUM, 1024, 0, stream>>>(pool, cntG, anch, reg, imh, imw,
                                               sortedKey, candBox, candArea, keepInit);
    iou_kernel<<<dim3(C_NUM, 16), 256, 0, stream>>>(candBox, candArea, supW);
    nmsout_kernel<<<C_NUM, 1024, 0, stream>>>(supW, keepInit, sortedKey, candBox,
                                              (float*)d_out);
}

// Round 6
// 179.609 us; speedup vs baseline: 4.2562x; 1.1236x over previous
//
#include <hip/hip_runtime.h>
#include <hip/hip_bf16.h>
#include <math.h>

typedef unsigned long long u64;
typedef unsigned int u32;

#define C_NUM 80
#define TOPK 1000
#define CAP 2048
#define HB 128
#define STG 32
#define SCORE_THR 0.05f
#define IOU_THR 0.5f
#define GRID_SCAN 256

// correctly-rounded-ish f32 exp via double (matched reference bit-exact rounds 1-5)
__device__ __forceinline__ float exp_cr(float x) {
    return (float)exp((double)x);
}

// Exact f32 replication of reference decode + clip (no FMA contraction).
__device__ __forceinline__ void decode_box(const float* __restrict__ anch,
                                           const float* __restrict__ reg,
                                           int a, float fw, float fh, float4* out) {
#pragma clang fp contract(off)
    float a0 = anch[(size_t)a * 4 + 0], a1 = anch[(size_t)a * 4 + 1];
    float a2 = anch[(size_t)a * 4 + 2], a3 = anch[(size_t)a * 4 + 3];
    float d0 = reg[(size_t)a * 4 + 0], d1 = reg[(size_t)a * 4 + 1];
    float d2 = reg[(size_t)a * 4 + 2], d3 = reg[(size_t)a * 4 + 3];
    float w = a2 - a0, h = a3 - a1;
    float cx = a0 + 0.5f * w, cy = a1 + 0.5f * h;
    float dx = d0 * 0.1f, dy = d1 * 0.1f, dw = d2 * 0.2f, dh = d3 * 0.2f;
    float t1 = dx * w; float pcx = cx + t1;
    float t2 = dy * h; float pcy = cy + t2;
    float pw = exp_cr(dw) * w;
    float ph = exp_cr(dh) * h;
    float x1 = pcx - 0.5f * pw, y1 = pcy - 0.5f * ph;
    float x2 = pcx + 0.5f * pw, y2 = pcy + 0.5f * ph;
    x1 = fminf(fmaxf(x1, 0.0f), fw);
    y1 = fminf(fmaxf(y1, 0.0f), fh);
    x2 = fminf(fmaxf(x2, 0.0f), fw);
    y2 = fminf(fmaxf(y2, 0.0f), fh);
    *out = make_float4(x1, y1, x2, y2);
}

// Per-block private histogram slices; no global atomics at all.
__global__ __launch_bounds__(1024)
void hist_kernel(const float4* __restrict__ cls4, u32* __restrict__ slices, int nvec) {
    __shared__ u32 h[C_NUM * HB];                 // 40 KB
    int tid = threadIdx.x;
    for (int i = tid; i < C_NUM * HB; i += 1024) h[i] = 0u;
    __syncthreads();
    int gid = blockIdx.x * 1024 + tid;
    const int stride = GRID_SCAN * 1024;          // float4 units
    const int dC = (stride * 4) % C_NUM;
    int c0 = (gid * 4) % C_NUM;
    for (int v = gid; v < nvec; v += stride) {
        float4 f = cls4[v];
        float e[4] = {f.x, f.y, f.z, f.w};
        int cc = c0;
#pragma unroll
        for (int k = 0; k < 4; ++k) {
            int t = (((int)__float_as_uint(e[k])) - 0x3F000000) >> 16;
            if (t > 0) {
                t = t > HB - 1 ? HB - 1 : t;
                atomicAdd(&h[cc * HB + t], 1u);   // LDS atomic only
            }
            cc++; if (cc == C_NUM) cc = 0;
        }
        c0 += dC; if (c0 >= C_NUM) c0 -= C_NUM;
    }
    __syncthreads();
    u32* my = slices + (size_t)blockIdx.x * (C_NUM * HB);
    for (int i = tid; i < C_NUM * HB; i += 1024) my[i] = h[i];
}

// Per-class: parallel reduce of 256 slices (8 groups x 128 buckets) -> suffix-sum
// -> threshold bit-edge.
__global__ __launch_bounds__(1024)
void thr_kernel(const u32* __restrict__ slices, u32* __restrict__ thrG) {
    __shared__ u32 part[8][HB];
    __shared__ u32 s[HB];
    __shared__ int bsel;
    int c = blockIdx.x, tid = threadIdx.x;
    int b = tid & (HB - 1), g = tid >> 7;         // 8 groups of 32 slices each
    u32 sum = 0;
    const u32* base = slices + c * HB + b;
    for (int sl = g * 32; sl < g * 32 + 32; ++sl)
        sum += base[(size_t)sl * (C_NUM * HB)];   // lanes read consecutive -> coalesced
    part[g][b] = sum;
    if (tid == 0) bsel = 0;
    __syncthreads();
    if (tid < HB) {
        u32 t = 0;
#pragma unroll
        for (int g2 = 0; g2 < 8; ++g2) t += part[g2][tid];
        s[tid] = t;
    }
    __syncthreads();
    for (int d = 1; d < HB; d <<= 1) {
        u32 v = 0;
        if (tid < HB) v = s[tid] + ((tid + d < HB) ? s[tid + d] : 0u);
        __syncthreads();
        if (tid < HB) s[tid] = v;
        __syncthreads();
    }
    if (tid < HB) {
        u32 me = s[tid];
        u32 nxt = (tid < HB - 1) ? s[tid + 1] : 0u;
        if (me >= (u32)TOPK && (tid == HB - 1 || nxt < (u32)TOPK)) bsel = tid;
    }
    __syncthreads();
    if (tid == 0) {
        int bb = bsel;
        thrG[c] = (bb == 0) ? 0u : (u32)(0x3F000000 + (bb << 16));
    }
}

// Gather with block-local LDS staging; ONE bulk reservation atomic per (class,block).
__global__ __launch_bounds__(1024)
void gather_kernel(const float4* __restrict__ cls4, const u32* __restrict__ thrG,
                   u32* __restrict__ cntG, u64* __restrict__ pool, int nvec) {
    __shared__ int thrS[C_NUM];
    __shared__ u32 lcnt[C_NUM];
    __shared__ u32 lbase[C_NUM];
    __shared__ u64 stage[C_NUM * STG];            // 20 KB
    int tid = threadIdx.x;
    if (tid < C_NUM) { thrS[tid] = (int)thrG[tid]; lcnt[tid] = 0u; }
    __syncthreads();

    int gid = blockIdx.x * 1024 + tid;
    const int stride = GRID_SCAN * 1024;
    const int dA = (stride * 4) / C_NUM;
    const int dC = (stride * 4) % C_NUM;
    int base = gid * 4;
    int aa0 = base / C_NUM;
    int c0 = base - aa0 * C_NUM;
    for (int v = gid; v < nvec; v += stride) {
        float4 f = cls4[v];
        float e[4] = {f.x, f.y, f.z, f.w};
        int cc = c0, aa = aa0;
#pragma unroll
        for (int k = 0; k < 4; ++k) {
            int bits = (int)__float_as_uint(e[k]);
            if (bits >= thrS[cc]) {
                u64 key = ((u64)(u32)bits << 32) | (u64)(u32)(~(u32)aa);
                u32 p = atomicAdd(&lcnt[cc], 1u);             // LDS atomic
                if (p < STG) stage[cc * STG + p] = key;
                else {                                         // rare overflow fallback
                    u32 q = atomicAdd(&cntG[cc], 1u);
                    if (q < CAP) pool[(size_t)cc * CAP + q] = key;
                }
            }
            cc++; if (cc == C_NUM) { cc = 0; aa++; }
        }
        c0 += dC;
        if (c0 >= C_NUM) { c0 -= C_NUM; aa0 += dA + 1; } else aa0 += dA;
    }
    __syncthreads();
    if (tid < C_NUM) {
        u32 nl = lcnt[tid]; if (nl > STG) nl = STG;
        lbase[tid] = nl ? atomicAdd(&cntG[tid], nl) : 0u;      // one atomic per class
        lcnt[tid] = nl;
    }
    __syncthreads();
    for (int i = tid; i < C_NUM * STG; i += 1024) {
        int c = i >> 5, k = i & (STG - 1);
        if ((u32)k < lcnt[c]) {
            u32 q = lbase[c] + (u32)k;
            if (q < CAP) pool[(size_t)c * CAP + q] = stage[i];
        }
    }
}

// Rank-sort spread over all CUs: grid (C_NUM, 8) x 256. Each block loads the
// class pool into LDS (b128 pairs), each thread ranks ONE candidate against all
// keys (rank = # strictly greater; keys distinct via ~idx), then decodes and
// scatter-writes by rank. Slots never written are pre-zeroed by memset.
__global__ __launch_bounds__(256)
void rank_kernel(const u64* __restrict__ pool, const u32* __restrict__ cntG,
                 const float* __restrict__ anchors, const float* __restrict__ regs,
                 const int* __restrict__ imh, const int* __restrict__ imw,
                 u64* __restrict__ sortedKey, float4* __restrict__ candBox,
                 float* __restrict__ candArea) {
    __shared__ __align__(16) u64 keys[CAP];       // 16 KB
    int c = blockIdx.x, q = blockIdx.y, tid = threadIdx.x;
    int n = (int)cntG[c]; if (n > CAP) n = CAP;
    if (q * 256 >= n) return;                      // uniform: whole block idle
    for (int i = tid; i < n; i += 256) keys[i] = pool[(size_t)c * CAP + i];
    __syncthreads();
    int my = q * 256 + tid;
    u64 k0 = (my < n) ? keys[my] : ~0ull;          // sentinel: rank 0, write-guarded
    int r0 = 0;
    int j = 0;
    for (; j + 8 <= n; j += 8) {
        ulonglong2 p0 = *(const ulonglong2*)&keys[j];
        ulonglong2 p1 = *(const ulonglong2*)&keys[j + 2];
        ulonglong2 p2 = *(const ulonglong2*)&keys[j + 4];
        ulonglong2 p3 = *(const ulonglong2*)&keys[j + 6];
        r0 += (int)(p0.x > k0) + (int)(p0.y > k0)
            + (int)(p1.x > k0) + (int)(p1.y > k0)
            + (int)(p2.x > k0) + (int)(p2.y > k0)
            + (int)(p3.x > k0) + (int)(p3.y > k0);
    }
    for (; j < n; ++j) r0 += (int)(keys[j] > k0);
    if (my < n && r0 < TOPK) {
        float sc = __uint_as_float((u32)(k0 >> 32));
        int a = (int)(~(u32)k0);
        float fw = (float)(*imw), fh = (float)(*imh);
        float4 bx = make_float4(0.f, 0.f, 0.f, 0.f);
        if (sc > SCORE_THR) decode_box(anchors, regs, a, fw, fh, &bx);
        int g = c * TOPK + r0;
        sortedKey[g] = k0;
        candBox[g] = bx;
        candArea[g] = fmaxf(bx.z - bx.x, 0.0f) * fmaxf(bx.w - bx.y, 0.0f);
    }
}

// Suppression bit-matrix, triangular, rows interleaved mod 16 for load balance.
// grid (C_NUM, 16) x 256 = 1280 blocks = exactly 5 blocks/CU (LDS 5x20.25KB fits).
// Division eliminated: RN32(inter/d) > 0.5f  <=>  inter > (0.5+2^-25)*d (exact in
// double, tie unreachable for f32 operands) -> decisions bit-identical.
__global__ __launch_bounds__(256)
void iou_kernel(const float4* __restrict__ candBox, const float* __restrict__ candArea,
                u64* __restrict__ supW) {
#pragma clang fp contract(off)
    __shared__ float4 box[TOPK];                  // 16 KB
    __shared__ float area[TOPK];                  //  4 KB
    int c = blockIdx.x, q = blockIdx.y;
    int tid = threadIdx.x, lane = tid & 63, wave = tid >> 6;
    for (int i = tid; i < TOPK; i += 256) {
        box[i] = candBox[(size_t)c * TOPK + i];
        area[i] = candArea[(size_t)c * TOPK + i];
    }
    __syncthreads();
    const double CC = 0.5 + 0x1p-25;
    for (int t = wave; 16 * t + q < TOPK; t += 4) {
        int i = 16 * t + q;
        float4 bi = box[i];
        float ai = area[i];
        int jw0 = i >> 6;
        u64* supRow = supW + ((size_t)c * TOPK + i) * 16;
        if (lane < jw0) supRow[lane] = 0ull;
#pragma unroll 4
        for (int jw = jw0; jw < 16; ++jw) {
            int j = (jw << 6) | lane;
            bool sup = false;
            if (j > i && j < TOPK) {
                float4 bj = box[j];
                float ltx = fmaxf(bi.x, bj.x), lty = fmaxf(bi.y, bj.y);
                float rbx = fminf(bi.z, bj.z), rby = fminf(bi.w, bj.w);
                float ww = fmaxf(rbx - ltx, 0.0f), hh = fmaxf(rby - lty, 0.0f);
                float inter = ww * hh;
                float uni = (ai + area[j]) - inter;
                float d = fmaxf(uni, 1e-8f);
                sup = (double)inter > CC * (double)d;
            }
            u64 mm = __ballot(sup);
            if (lane == 0) supRow[jw] = mm;
        }
    }
}

// 1024 threads/class: 16 waves bulk-copy sup matrix (128 KB) into LDS; validity
// ballot recomputed from sortedKey scores; wave 0 runs the greedy pass with
// readlane (SALU broadcast) in the chain; all threads write output coalesced.
__global__ __launch_bounds__(1024)
void nmsout_kernel(const u64* __restrict__ supW, const u64* __restrict__ sortedKey,
                   const float4* __restrict__ candBox, float* __restrict__ out) {
    __shared__ __align__(16) u64 supLds[TOPK * 16];   // 128 KB
    __shared__ u64 keepI[16];
    __shared__ u64 keepF[16];
    int c = blockIdx.x, tid = threadIdx.x;
    int lane = tid & 63, wave = tid >> 6;

    u64 key = (tid < TOPK) ? sortedKey[c * TOPK + tid] : 0ull;
    float sc = __uint_as_float((u32)(key >> 32));
    bool valid = (tid < TOPK) && (sc > SCORE_THR);
    u64 mb = __ballot(valid);
    if (lane == 0) keepI[wave] = mb;

    const float4* src = (const float4*)(supW + (size_t)c * TOPK * 16);
    float4* dst = (float4*)supLds;
    for (int i = tid; i < TOPK * 8; i += 1024) dst[i] = src[i];
    __syncthreads();

    if (tid < 64) {
        u64 kw = (lane < 16) ? keepI[lane] : 0ull;
        u64 buf[8];
#pragma unroll
        for (int u = 0; u < 8; ++u)
            buf[u] = (lane < 16) ? supLds[u * 16 + lane] : 0ull;
        for (int i0 = 0; i0 < TOPK; i0 += 8) {
#pragma unroll
            for (int u = 0; u < 8; ++u) {
                int i = i0 + u;
                u32 wlo = (u32)__builtin_amdgcn_readlane((int)(u32)kw, i >> 6);
                u32 whi = (u32)__builtin_amdgcn_readlane((int)(u32)(kw >> 32), i >> 6);
                u32 sel = (i & 32) ? whi : wlo;
                u64 m = (u64)0 - (u64)((sel >> (i & 31)) & 1u);
                kw &= ~(buf[u] & m);
                int nx = i + 8;
                buf[u] = (nx < TOPK && lane < 16) ? supLds[nx * 16 + lane] : 0ull;
            }
        }
        if (lane < 16) keepF[lane] = kw;
    }
    __syncthreads();

    if (tid < TOPK) {
        bool keep = (keepF[tid >> 6] >> (tid & 63)) & 1ull;
        int g = c * TOPK + tid;
        out[g] = keep ? sc : 0.0f;
        out[C_NUM * TOPK + g] = keep ? (float)c : -1.0f;
        float4 b = keep ? candBox[g] : make_float4(0.f, 0.f, 0.f, 0.f);
        ((float4*)(out + 2 * C_NUM * TOPK))[g] = b;
    }
}

extern "C" void kernel_launch(void* const* d_in, const int* in_sizes, int n_in,
                              void* d_out, int out_size, void* d_ws, size_t ws_size,
                              hipStream_t stream) {
    const float* cls  = (const float*)d_in[0];
    const float* reg  = (const float*)d_in[1];
    const float* anch = (const float*)d_in[2];
    const int* imh    = (const int*)d_in[3];
    const int* imw    = (const int*)d_in[4];
    int A = in_sizes[2] / 4;
    int nvec = (A * C_NUM) / 4;

    char* w = (char*)d_ws;
    size_t off = 0;
    auto alloc = [&](size_t bytes) -> void* {
        off = (off + 255) & ~(size_t)255;
        void* p = w + off;
        off += bytes;
        return p;
    };
    u32*    cntG      = (u32*)   alloc((size_t)C_NUM * 4);
    u32*    thrG      = (u32*)   alloc((size_t)C_NUM * 4);
    u32*    slices    = (u32*)   alloc((size_t)GRID_SCAN * C_NUM * HB * 4);   // 10.5 MB
    u64*    pool      = (u64*)   alloc((size_t)C_NUM * CAP * 8);              // 1.3 MB
    // contiguous zero-fill span: sortedKey + candBox + candArea
    u64*    sortedKey = (u64*)   alloc((size_t)C_NUM * TOPK * 8);
    float4* candBox   = (float4*)alloc((size_t)C_NUM * TOPK * 16);
    float*  candArea  = (float*) alloc((size_t)C_NUM * TOPK * 4);
    u64*    supW      = (u64*)   alloc((size_t)C_NUM * TOPK * 16 * 8);        // 10.2 MB
    size_t zspan = (char*)(candArea + (size_t)C_NUM * TOPK) - (char*)sortedKey;

    hipMemsetAsync(cntG, 0, (size_t)C_NUM * 4, stream);
    hipMemsetAsync(sortedKey, 0, zspan, stream);
    hist_kernel<<<GRID_SCAN, 1024, 0, stream>>>((const float4*)cls, slices, nvec);
    thr_kernel<<<C_NUM, 1024, 0, stream>>>(slices, thrG);
    gather_kernel<<<GRID_SCAN, 1024, 0, stream>>>((const float4*)cls, thrG, cntG, pool, nvec);
    rank_kernel<<<dim3(C_NUM, 8), 256, 0, stream>>>(pool, cntG, anch, reg, imh, imw,
                                                    sortedKey, candBox, candArea);
    iou_kernel<<<dim3(C_NUM, 16), 256, 0, stream>>>(candBox, candArea, supW);
    nmsout_kernel<<<C_NUM, 1024, 0, stream>>>(supW, sortedKey, candBox, (float*)d_out);
}